// Round 1
// baseline (1700.586 us; speedup 1.0000x reference)
//
#include <hip/hip_runtime.h>
#include <math.h>

#define BT 2
#define TT 1024
#define HH 1024
#define NHEADS 16
#define NKVH 4
#define HDIM 64
#define NE 64
#define TOPK 8
#define II 512
#define NTOK 2048

// ---------------- RMSNorm: one block per token, H=1024 ----------------
__global__ __launch_bounds__(256) void rmsnorm_kernel(
    const float* __restrict__ x, const float* __restrict__ w,
    float* __restrict__ out)
{
  int n = blockIdx.x;
  const float* xr = x + (size_t)n * HH;
  float vals[4];
  float ss = 0.f;
  #pragma unroll
  for (int i = 0; i < 4; ++i) {
    float v = xr[threadIdx.x + i * 256];
    vals[i] = v; ss += v * v;
  }
  #pragma unroll
  for (int off = 32; off; off >>= 1) ss += __shfl_xor(ss, off, 64);
  __shared__ float red[4];
  int lane = threadIdx.x & 63, wid = threadIdx.x >> 6;
  if (lane == 0) red[wid] = ss;
  __syncthreads();
  float tot = red[0] + red[1] + red[2] + red[3];
  float scale = rsqrtf(tot * (1.0f / HH) + 1e-6f);
  float* orow = out + (size_t)n * HH;
  #pragma unroll
  for (int i = 0; i < 4; ++i) {
    int c = threadIdx.x + i * 256;
    orow[c] = vals[i] * scale * w[c];
  }
}

// ---------------- Generic fp32 GEMM: C[M,Nc] = A[M,K] @ B[K,Nc] (+resid) ----
// 64x64 tile, BK=32, 256 threads, 4x4 micro-tile. M,Nc,K multiples of 64/32.
__global__ __launch_bounds__(256) void gemm_kernel(
    const float* __restrict__ A, const float* __restrict__ B,
    float* __restrict__ C, const float* __restrict__ resid,
    int M, int Nc, int Kd)
{
  __shared__ float As[32][68];
  __shared__ float Bs[32][68];
  int t = threadIdx.x;
  int n0 = blockIdx.x * 64;
  int m0 = blockIdx.y * 64;
  int tx = t & 15, ty = t >> 4;
  float acc[4][4] = {{0.f}};
  for (int k0 = 0; k0 < Kd; k0 += 32) {
    #pragma unroll
    for (int i = 0; i < 8; ++i) {
      int e = t + i * 256;
      int kk = e & 31, row = e >> 5;
      As[kk][row] = A[(size_t)(m0 + row) * Kd + k0 + kk];
    }
    #pragma unroll
    for (int i = 0; i < 8; ++i) {
      int e = t + i * 256;
      int col = e & 63, kr = e >> 6;
      Bs[kr][col] = B[(size_t)(k0 + kr) * Nc + n0 + col];
    }
    __syncthreads();
    #pragma unroll
    for (int kk = 0; kk < 32; ++kk) {
      float4 a4 = *(const float4*)&As[kk][ty * 4];
      float4 b4 = *(const float4*)&Bs[kk][tx * 4];
      float a[4] = {a4.x, a4.y, a4.z, a4.w};
      float b[4] = {b4.x, b4.y, b4.z, b4.w};
      #pragma unroll
      for (int i = 0; i < 4; ++i)
        #pragma unroll
        for (int j = 0; j < 4; ++j)
          acc[i][j] += a[i] * b[j];
    }
    __syncthreads();
  }
  #pragma unroll
  for (int i = 0; i < 4; ++i) {
    int r = m0 + ty * 4 + i;
    #pragma unroll
    for (int j = 0; j < 4; ++j) {
      int c = n0 + tx * 4 + j;
      float v = acc[i][j];
      if (resid) v += resid[(size_t)r * Nc + c];
      C[(size_t)r * Nc + c] = v;
    }
  }
}

// ---------------- RoPE (in place) ----------------
__global__ void rope_kernel(float* __restrict__ buf,
    const float* __restrict__ cosb, const float* __restrict__ sinb, int nheads)
{
  int idx = blockIdx.x * blockDim.x + threadIdx.x;
  int d = idx & 31;
  int tmp = idx >> 5;
  int hh = tmp % nheads;
  int n = tmp / nheads;
  if (n >= NTOK) return;
  int tp = n & (TT - 1);
  float c0 = cosb[tp * HDIM + d];
  float s0 = sinb[tp * HDIM + d];
  float c1 = cosb[tp * HDIM + d + 32];
  float s1 = sinb[tp * HDIM + d + 32];
  float* base = buf + (size_t)n * nheads * HDIM + hh * HDIM;
  float u0 = base[d], u1 = base[d + 32];
  base[d]      = u0 * c0 - u1 * s0;
  base[d + 32] = u1 * c1 + u0 * s1;
}

// ---------------- Flash attention, fp32, 64-row Q tiles, GQA ----------------
__global__ __launch_bounds__(256) void attn_kernel(
    const float* __restrict__ qb, const float* __restrict__ kb,
    const float* __restrict__ vb, float* __restrict__ ao)
{
  const int qt = blockIdx.x;
  const int bh = blockIdx.y;
  const int b = bh >> 4;
  const int h = bh & 15;
  const int kvh = h >> 2;
  const int q0 = qt * 64;

  __shared__ float Qs[64][68];   // [d][r]
  __shared__ float KPs[64][68];  // Ks: [d][c]; later Ps: [c][r]
  __shared__ float Vs[64][68];   // [c][d]

  int t = threadIdx.x;
  int tx = t & 15, ty = t >> 4;

  #pragma unroll
  for (int i = 0; i < 4; ++i) {
    int e = t + i * 256;
    int r = e >> 4;
    int d = (e & 15) * 4;
    const float* src = qb + ((size_t)(b * TT + q0 + r)) * (NHEADS * HDIM) + h * HDIM + d;
    float4 qv = *(const float4*)src;
    Qs[d + 0][r] = qv.x; Qs[d + 1][r] = qv.y; Qs[d + 2][r] = qv.z; Qs[d + 3][r] = qv.w;
  }

  float m_i[4], l_i[4], o[4][4];
  #pragma unroll
  for (int i = 0; i < 4; ++i) {
    m_i[i] = -1e30f; l_i[i] = 0.f;
    #pragma unroll
    for (int j = 0; j < 4; ++j) o[i][j] = 0.f;
  }

  for (int jt = 0; jt <= qt; ++jt) {
    int j0 = jt * 64;
    __syncthreads();
    #pragma unroll
    for (int i = 0; i < 4; ++i) {
      int e = t + i * 256;
      int r = e >> 4;
      int d = (e & 15) * 4;
      const float* srcK = kb + ((size_t)(b * TT + j0 + r)) * (NKVH * HDIM) + kvh * HDIM + d;
      float4 kv = *(const float4*)srcK;
      KPs[d + 0][r] = kv.x; KPs[d + 1][r] = kv.y; KPs[d + 2][r] = kv.z; KPs[d + 3][r] = kv.w;
      const float* srcV = vb + ((size_t)(b * TT + j0 + r)) * (NKVH * HDIM) + kvh * HDIM + d;
      *(float4*)&Vs[r][d] = *(const float4*)srcV;
    }
    __syncthreads();
    // S = Q K^T
    float s[4][4] = {{0.f}};
    #pragma unroll 8
    for (int d = 0; d < 64; ++d) {
      float4 a = *(const float4*)&Qs[d][ty * 4];
      float4 bb = *(const float4*)&KPs[d][tx * 4];
      float av[4] = {a.x, a.y, a.z, a.w};
      float bv[4] = {bb.x, bb.y, bb.z, bb.w};
      #pragma unroll
      for (int i = 0; i < 4; ++i)
        #pragma unroll
        for (int j = 0; j < 4; ++j)
          s[i][j] += av[i] * bv[j];
    }
    bool diag = (jt == qt);
    #pragma unroll
    for (int i = 0; i < 4; ++i) {
      int gr = q0 + ty * 4 + i;
      #pragma unroll
      for (int j = 0; j < 4; ++j) {
        int gc = j0 + tx * 4 + j;
        float val = s[i][j] * 0.125f;
        if (diag && gc > gr) val = -1e30f;
        s[i][j] = val;
      }
    }
    // online softmax (row group = 16 lanes sharing ty, within one wave)
    #pragma unroll
    for (int i = 0; i < 4; ++i) {
      float mx = fmaxf(fmaxf(s[i][0], s[i][1]), fmaxf(s[i][2], s[i][3]));
      #pragma unroll
      for (int off = 8; off; off >>= 1) mx = fmaxf(mx, __shfl_xor(mx, off, 64));
      float mnew = fmaxf(m_i[i], mx);
      float al = __expf(m_i[i] - mnew);
      float rs = 0.f;
      #pragma unroll
      for (int j = 0; j < 4; ++j) { float p = __expf(s[i][j] - mnew); s[i][j] = p; rs += p; }
      #pragma unroll
      for (int off = 8; off; off >>= 1) rs += __shfl_xor(rs, off, 64);
      l_i[i] = l_i[i] * al + rs;
      m_i[i] = mnew;
      #pragma unroll
      for (int j = 0; j < 4; ++j) o[i][j] *= al;
    }
    __syncthreads();   // all lanes done reading Ks before overwriting with Ps
    #pragma unroll
    for (int i = 0; i < 4; ++i)
      #pragma unroll
      for (int j = 0; j < 4; ++j)
        KPs[tx * 4 + j][ty * 4 + i] = s[i][j];
    __syncthreads();
    // O += P V
    #pragma unroll 8
    for (int c = 0; c < 64; ++c) {
      float4 p = *(const float4*)&KPs[c][ty * 4];
      float4 vv = *(const float4*)&Vs[c][tx * 4];
      float pv[4] = {p.x, p.y, p.z, p.w};
      float vvv[4] = {vv.x, vv.y, vv.z, vv.w};
      #pragma unroll
      for (int i = 0; i < 4; ++i)
        #pragma unroll
        for (int j = 0; j < 4; ++j)
          o[i][j] += pv[i] * vvv[j];
    }
  }
  #pragma unroll
  for (int i = 0; i < 4; ++i) {
    float inv = 1.0f / l_i[i];
    float4 ov;
    ov.x = o[i][0] * inv; ov.y = o[i][1] * inv; ov.z = o[i][2] * inv; ov.w = o[i][3] * inv;
    float* dst = ao + ((size_t)(b * TT + q0 + ty * 4 + i)) * (NHEADS * HDIM) + h * HDIM + tx * 4;
    *(float4*)dst = ov;
  }
}

// ---------------- Router top-k: one wave per token ----------------
__global__ __launch_bounds__(64) void topk_kernel(
    const float* __restrict__ logits, int* __restrict__ tki,
    float* __restrict__ tkw, int* __restrict__ counts)
{
  int n = blockIdx.x;
  int e = threadIdx.x;
  float cur = logits[(size_t)n * NE + e];
  float mymv = 0.f; int mymi = 0;
  float mx0 = 0.f, ssum = 0.f;
  for (int it = 0; it < TOPK; ++it) {
    float mv = cur; int mi = e;
    #pragma unroll
    for (int off = 32; off; off >>= 1) {
      float ov = __shfl_xor(mv, off, 64);
      int oi = __shfl_xor(mi, off, 64);
      if (ov > mv || (ov == mv && oi < mi)) { mv = ov; mi = oi; }
    }
    if (it == 0) mx0 = mv;
    ssum += __expf(mv - mx0);
    if (e == it) { mymv = mv; mymi = mi; }
    if (e == mi) cur = -3.0e38f;
  }
  if (e < TOPK) {
    tki[n * TOPK + e] = mymi;
    tkw[n * TOPK + e] = __expf(mymv - mx0) / ssum;   // subset softmax == renormalized
    atomicAdd(&counts[mymi], 1);
  }
}

__global__ void scan_kernel(const int* __restrict__ counts,
    int* __restrict__ offs, int* __restrict__ curs)
{
  if (threadIdx.x == 0 && blockIdx.x == 0) {
    int acc = 0;
    for (int e = 0; e < NE; ++e) { offs[e] = acc; curs[e] = acc; acc += counts[e]; }
    offs[NE] = acc;
  }
}

__global__ void fill_kernel(const int* __restrict__ tki,
    const float* __restrict__ tkw, int* __restrict__ curs,
    int* __restrict__ slott, float* __restrict__ slotw)
{
  int i = blockIdx.x * blockDim.x + threadIdx.x;
  if (i >= NTOK * TOPK) return;
  int e = tki[i];
  int pos = atomicAdd(&curs[e], 1);
  slott[pos] = i >> 3;
  slotw[pos] = tkw[i];
}

// ---------------- MoE gate/up fused: g = silu(A@Wg[e]) * (A@Wu[e]) ----------
__global__ __launch_bounds__(256) void moe_gateup_kernel(
    const float* __restrict__ f, const float* __restrict__ Wg,
    const float* __restrict__ Wu, const int* __restrict__ offs,
    const int* __restrict__ slott, float* __restrict__ g)
{
  int e = blockIdx.z;
  int base = offs[e];
  int Me = offs[e + 1] - base;
  int r0 = blockIdx.y * 64;
  if (r0 >= Me) return;
  int n0 = blockIdx.x * 64;

  __shared__ float As[32][68];
  __shared__ float Bg[32][68];
  __shared__ float Bu[32][68];
  __shared__ int rowtok[64];

  int t = threadIdx.x;
  if (t < 64) {
    int rr = r0 + t;
    rowtok[t] = slott[base + ((rr < Me) ? rr : (Me - 1))];
  }
  __syncthreads();
  int tx = t & 15, ty = t >> 4;
  float ag[4][4] = {{0.f}}, au[4][4] = {{0.f}};
  const float* WgE = Wg + (size_t)e * HH * II;
  const float* WuE = Wu + (size_t)e * HH * II;
  for (int k0 = 0; k0 < HH; k0 += 32) {
    #pragma unroll
    for (int i = 0; i < 8; ++i) {
      int el = t + i * 256;
      int kk = el & 31, row = el >> 5;
      As[kk][row] = f[(size_t)rowtok[row] * HH + k0 + kk];
    }
    #pragma unroll
    for (int i = 0; i < 8; ++i) {
      int el = t + i * 256;
      int col = el & 63, kr = el >> 6;
      Bg[kr][col] = WgE[(size_t)(k0 + kr) * II + n0 + col];
      Bu[kr][col] = WuE[(size_t)(k0 + kr) * II + n0 + col];
    }
    __syncthreads();
    #pragma unroll
    for (int kk = 0; kk < 32; ++kk) {
      float4 a4 = *(const float4*)&As[kk][ty * 4];
      float4 bg4 = *(const float4*)&Bg[kk][tx * 4];
      float4 bu4 = *(const float4*)&Bu[kk][tx * 4];
      float a[4] = {a4.x, a4.y, a4.z, a4.w};
      float bgv[4] = {bg4.x, bg4.y, bg4.z, bg4.w};
      float buv[4] = {bu4.x, bu4.y, bu4.z, bu4.w};
      #pragma unroll
      for (int i = 0; i < 4; ++i)
        #pragma unroll
        for (int j = 0; j < 4; ++j) {
          ag[i][j] += a[i] * bgv[j];
          au[i][j] += a[i] * buv[j];
        }
    }
    __syncthreads();
  }
  #pragma unroll
  for (int i = 0; i < 4; ++i) {
    int r = ty * 4 + i;
    if (r0 + r >= Me) continue;
    #pragma unroll
    for (int j = 0; j < 4; ++j) {
      float gv = ag[i][j];
      float sig = 1.0f / (1.0f + __expf(-gv));
      g[(size_t)(base + r0 + r) * II + n0 + tx * 4 + j] = gv * sig * au[i][j];
    }
  }
}

// ---------------- MoE down + weighted scatter-add into out ----------------
__global__ __launch_bounds__(256) void moe_down_kernel(
    const float* __restrict__ g, const float* __restrict__ Wd,
    const int* __restrict__ offs, const int* __restrict__ slott,
    const float* __restrict__ slotw, float* __restrict__ out)
{
  int e = blockIdx.z;
  int base = offs[e];
  int Me = offs[e + 1] - base;
  int r0 = blockIdx.y * 64;
  if (r0 >= Me) return;
  int n0 = blockIdx.x * 64;

  __shared__ float As[32][68];
  __shared__ float Bs[32][68];

  int t = threadIdx.x;
  int tx = t & 15, ty = t >> 4;
  float acc[4][4] = {{0.f}};
  const float* WdE = Wd + (size_t)e * II * HH;
  for (int k0 = 0; k0 < II; k0 += 32) {
    #pragma unroll
    for (int i = 0; i < 8; ++i) {
      int el = t + i * 256;
      int kk = el & 31, row = el >> 5;
      int rr = r0 + row; if (rr >= Me) rr = Me - 1;
      As[kk][row] = g[(size_t)(base + rr) * II + k0 + kk];
    }
    #pragma unroll
    for (int i = 0; i < 8; ++i) {
      int el = t + i * 256;
      int col = el & 63, kr = el >> 6;
      Bs[kr][col] = WdE[(size_t)(k0 + kr) * HH + n0 + col];
    }
    __syncthreads();
    #pragma unroll
    for (int kk = 0; kk < 32; ++kk) {
      float4 a4 = *(const float4*)&As[kk][ty * 4];
      float4 b4 = *(const float4*)&Bs[kk][tx * 4];
      float a[4] = {a4.x, a4.y, a4.z, a4.w};
      float b[4] = {b4.x, b4.y, b4.z, b4.w};
      #pragma unroll
      for (int i = 0; i < 4; ++i)
        #pragma unroll
        for (int j = 0; j < 4; ++j)
          acc[i][j] += a[i] * b[j];
    }
    __syncthreads();
  }
  #pragma unroll
  for (int i = 0; i < 4; ++i) {
    int r = ty * 4 + i;
    if (r0 + r >= Me) continue;
    int slot = base + r0 + r;
    int tok = slott[slot];
    float w = slotw[slot];
    #pragma unroll
    for (int j = 0; j < 4; ++j)
      atomicAdd(&out[(size_t)tok * HH + n0 + tx * 4 + j], w * acc[i][j]);
  }
}

__global__ void copy_kernel(const float* __restrict__ src, float* __restrict__ dst)
{
  int i = blockIdx.x * blockDim.x + threadIdx.x;
  ((float4*)dst)[i] = ((const float4*)src)[i];
}

extern "C" void kernel_launch(void* const* d_in, const int* in_sizes, int n_in,
                              void* d_out, int out_size, void* d_ws, size_t ws_size,
                              hipStream_t stream)
{
  const float* x    = (const float*)d_in[0];
  const float* cosb = (const float*)d_in[1];
  const float* sinb = (const float*)d_in[2];
  const float* ln1  = (const float*)d_in[3];
  const float* ln2  = (const float*)d_in[4];
  const float* Wq   = (const float*)d_in[5];
  const float* Wk   = (const float*)d_in[6];
  const float* Wv   = (const float*)d_in[7];
  const float* Wo   = (const float*)d_in[8];
  const float* Wr   = (const float*)d_in[9];
  const float* Wg   = (const float*)d_in[10];
  const float* Wu   = (const float*)d_in[11];
  const float* Wd   = (const float*)d_in[12];
  float* out = (float*)d_out;
  float* logits = out + (size_t)NTOK * HH;

  float* ws = (float*)d_ws;
  float* h     = ws;
  float* qb    = h   + (size_t)NTOK * HH;
  float* kb    = qb  + (size_t)NTOK * HH;
  float* vb    = kb  + (size_t)NTOK * NKVH * HDIM;
  float* ao    = vb  + (size_t)NTOK * NKVH * HDIM;
  float* x2    = ao  + (size_t)NTOK * HH;
  float* f     = x2  + (size_t)NTOK * HH;
  float* g     = f   + (size_t)NTOK * HH;
  float* slotw = g   + (size_t)NTOK * TOPK * II;
  float* tkw   = slotw + NTOK * TOPK;
  int* tki     = (int*)(tkw + NTOK * TOPK);
  int* slott   = tki + NTOK * TOPK;
  int* counts  = slott + NTOK * TOPK;
  int* offs    = counts + NE;
  int* curs    = offs + NE + 1;

  // attention branch
  rmsnorm_kernel<<<NTOK, 256, 0, stream>>>(x, ln1, h);
  gemm_kernel<<<dim3(16, 32), 256, 0, stream>>>(h, Wq, qb, nullptr, NTOK, 1024, 1024);
  gemm_kernel<<<dim3(4, 32), 256, 0, stream>>>(h, Wk, kb, nullptr, NTOK, 256, 1024);
  gemm_kernel<<<dim3(4, 32), 256, 0, stream>>>(h, Wv, vb, nullptr, NTOK, 256, 1024);
  rope_kernel<<<4096, 256, 0, stream>>>(qb, cosb, sinb, NHEADS);
  rope_kernel<<<1024, 256, 0, stream>>>(kb, cosb, sinb, NKVH);
  attn_kernel<<<dim3(16, 32), 256, 0, stream>>>(qb, kb, vb, ao);
  gemm_kernel<<<dim3(16, 32), 256, 0, stream>>>(ao, Wo, x2, x, NTOK, 1024, 1024);

  // MoE branch
  rmsnorm_kernel<<<NTOK, 256, 0, stream>>>(x2, ln2, f);
  gemm_kernel<<<dim3(1, 32), 256, 0, stream>>>(f, Wr, logits, nullptr, NTOK, 64, 1024);
  hipMemsetAsync(counts, 0, NE * sizeof(int), stream);
  topk_kernel<<<NTOK, 64, 0, stream>>>(logits, tki, tkw, counts);
  scan_kernel<<<1, 64, 0, stream>>>(counts, offs, curs);
  fill_kernel<<<64, 256, 0, stream>>>(tki, tkw, curs, slott, slotw);
  moe_gateup_kernel<<<dim3(8, 32, 64), 256, 0, stream>>>(f, Wg, Wu, offs, slott, g);
  copy_kernel<<<2048, 256, 0, stream>>>(x2, out);
  moe_down_kernel<<<dim3(16, 32, 64), 256, 0, stream>>>(g, Wd, offs, slott, slotw, out);
}

// Round 2
// 1132.958 us; speedup vs baseline: 1.5010x; 1.5010x over previous
//
#include <hip/hip_runtime.h>
#include <math.h>

#define BT 2
#define TT 1024
#define HH 1024
#define NHEADS 16
#define NKVH 4
#define HDIM 64
#define NE 64
#define TOPK 8
#define II 512
#define NTOK 2048

typedef unsigned short u16;
typedef __attribute__((ext_vector_type(8))) short bf16x8;
typedef __attribute__((ext_vector_type(4))) short bf16x4;
typedef __attribute__((ext_vector_type(4))) float f32x4;

__device__ __forceinline__ u16 f2bf(float x) {
  unsigned u = __float_as_uint(x);
  u += 0x7fff + ((u >> 16) & 1);   // RNE
  return (u16)(u >> 16);
}

// ---------------- RMSNorm: one block per token, H=1024 ----------------
__global__ __launch_bounds__(256) void rmsnorm_kernel(
    const float* __restrict__ x, const float* __restrict__ w,
    float* __restrict__ out)
{
  int n = blockIdx.x;
  const float* xr = x + (size_t)n * HH;
  float vals[4];
  float ss = 0.f;
  #pragma unroll
  for (int i = 0; i < 4; ++i) {
    float v = xr[threadIdx.x + i * 256];
    vals[i] = v; ss += v * v;
  }
  #pragma unroll
  for (int off = 32; off; off >>= 1) ss += __shfl_xor(ss, off, 64);
  __shared__ float red[4];
  int lane = threadIdx.x & 63, wid = threadIdx.x >> 6;
  if (lane == 0) red[wid] = ss;
  __syncthreads();
  float tot = red[0] + red[1] + red[2] + red[3];
  float scale = rsqrtf(tot * (1.0f / HH) + 1e-6f);
  float* orow = out + (size_t)n * HH;
  #pragma unroll
  for (int i = 0; i < 4; ++i) {
    int c = threadIdx.x + i * 256;
    orow[c] = vals[i] * scale * w[c];
  }
}

// ---------------- Generic fp32 GEMM (projections + router) ----------------
__global__ __launch_bounds__(256) void gemm_kernel(
    const float* __restrict__ A, const float* __restrict__ B,
    float* __restrict__ C, const float* __restrict__ resid,
    int M, int Nc, int Kd)
{
  __shared__ float As[32][68];
  __shared__ float Bs[32][68];
  int t = threadIdx.x;
  int n0 = blockIdx.x * 64;
  int m0 = blockIdx.y * 64;
  int tx = t & 15, ty = t >> 4;
  float acc[4][4] = {{0.f}};
  for (int k0 = 0; k0 < Kd; k0 += 32) {
    #pragma unroll
    for (int i = 0; i < 8; ++i) {
      int e = t + i * 256;
      int kk = e & 31, row = e >> 5;
      As[kk][row] = A[(size_t)(m0 + row) * Kd + k0 + kk];
    }
    #pragma unroll
    for (int i = 0; i < 8; ++i) {
      int e = t + i * 256;
      int col = e & 63, kr = e >> 6;
      Bs[kr][col] = B[(size_t)(k0 + kr) * Nc + n0 + col];
    }
    __syncthreads();
    #pragma unroll
    for (int kk = 0; kk < 32; ++kk) {
      float4 a4 = *(const float4*)&As[kk][ty * 4];
      float4 b4 = *(const float4*)&Bs[kk][tx * 4];
      float a[4] = {a4.x, a4.y, a4.z, a4.w};
      float b[4] = {b4.x, b4.y, b4.z, b4.w};
      #pragma unroll
      for (int i = 0; i < 4; ++i)
        #pragma unroll
        for (int j = 0; j < 4; ++j)
          acc[i][j] += a[i] * b[j];
    }
    __syncthreads();
  }
  #pragma unroll
  for (int i = 0; i < 4; ++i) {
    int r = m0 + ty * 4 + i;
    #pragma unroll
    for (int j = 0; j < 4; ++j) {
      int c = n0 + tx * 4 + j;
      float v = acc[i][j];
      if (resid) v += resid[(size_t)r * Nc + c];
      C[(size_t)r * Nc + c] = v;
    }
  }
}

// ---------------- RoPE (in place) ----------------
__global__ void rope_kernel(float* __restrict__ buf,
    const float* __restrict__ cosb, const float* __restrict__ sinb, int nheads)
{
  int idx = blockIdx.x * blockDim.x + threadIdx.x;
  int d = idx & 31;
  int tmp = idx >> 5;
  int hh = tmp % nheads;
  int n = tmp / nheads;
  if (n >= NTOK) return;
  int tp = n & (TT - 1);
  float c0 = cosb[tp * HDIM + d];
  float s0 = sinb[tp * HDIM + d];
  float c1 = cosb[tp * HDIM + d + 32];
  float s1 = sinb[tp * HDIM + d + 32];
  float* base = buf + (size_t)n * nheads * HDIM + hh * HDIM;
  float u0 = base[d], u1 = base[d + 32];
  base[d]      = u0 * c0 - u1 * s0;
  base[d + 32] = u1 * c1 + u0 * s1;
}

// ---------------- Flash attention, fp32, 64-row Q tiles, GQA ----------------
__global__ __launch_bounds__(256) void attn_kernel(
    const float* __restrict__ qb, const float* __restrict__ kb,
    const float* __restrict__ vb, float* __restrict__ ao)
{
  const int qt = blockIdx.x;
  const int bh = blockIdx.y;
  const int b = bh >> 4;
  const int h = bh & 15;
  const int kvh = h >> 2;
  const int q0 = qt * 64;

  __shared__ float Qs[64][68];   // [d][r]
  __shared__ float KPs[64][68];  // Ks: [d][c]; later Ps: [c][r]
  __shared__ float Vs[64][68];   // [c][d]

  int t = threadIdx.x;
  int tx = t & 15, ty = t >> 4;

  #pragma unroll
  for (int i = 0; i < 4; ++i) {
    int e = t + i * 256;
    int r = e >> 4;
    int d = (e & 15) * 4;
    const float* src = qb + ((size_t)(b * TT + q0 + r)) * (NHEADS * HDIM) + h * HDIM + d;
    float4 qv = *(const float4*)src;
    Qs[d + 0][r] = qv.x; Qs[d + 1][r] = qv.y; Qs[d + 2][r] = qv.z; Qs[d + 3][r] = qv.w;
  }

  float m_i[4], l_i[4], o[4][4];
  #pragma unroll
  for (int i = 0; i < 4; ++i) {
    m_i[i] = -1e30f; l_i[i] = 0.f;
    #pragma unroll
    for (int j = 0; j < 4; ++j) o[i][j] = 0.f;
  }

  for (int jt = 0; jt <= qt; ++jt) {
    int j0 = jt * 64;
    __syncthreads();
    #pragma unroll
    for (int i = 0; i < 4; ++i) {
      int e = t + i * 256;
      int r = e >> 4;
      int d = (e & 15) * 4;
      const float* srcK = kb + ((size_t)(b * TT + j0 + r)) * (NKVH * HDIM) + kvh * HDIM + d;
      float4 kv = *(const float4*)srcK;
      KPs[d + 0][r] = kv.x; KPs[d + 1][r] = kv.y; KPs[d + 2][r] = kv.z; KPs[d + 3][r] = kv.w;
      const float* srcV = vb + ((size_t)(b * TT + j0 + r)) * (NKVH * HDIM) + kvh * HDIM + d;
      *(float4*)&Vs[r][d] = *(const float4*)srcV;
    }
    __syncthreads();
    float s[4][4] = {{0.f}};
    #pragma unroll 8
    for (int d = 0; d < 64; ++d) {
      float4 a = *(const float4*)&Qs[d][ty * 4];
      float4 bb = *(const float4*)&KPs[d][tx * 4];
      float av[4] = {a.x, a.y, a.z, a.w};
      float bv[4] = {bb.x, bb.y, bb.z, bb.w};
      #pragma unroll
      for (int i = 0; i < 4; ++i)
        #pragma unroll
        for (int j = 0; j < 4; ++j)
          s[i][j] += av[i] * bv[j];
    }
    bool diag = (jt == qt);
    #pragma unroll
    for (int i = 0; i < 4; ++i) {
      int gr = q0 + ty * 4 + i;
      #pragma unroll
      for (int j = 0; j < 4; ++j) {
        int gc = j0 + tx * 4 + j;
        float val = s[i][j] * 0.125f;
        if (diag && gc > gr) val = -1e30f;
        s[i][j] = val;
      }
    }
    #pragma unroll
    for (int i = 0; i < 4; ++i) {
      float mx = fmaxf(fmaxf(s[i][0], s[i][1]), fmaxf(s[i][2], s[i][3]));
      #pragma unroll
      for (int off = 8; off; off >>= 1) mx = fmaxf(mx, __shfl_xor(mx, off, 64));
      float mnew = fmaxf(m_i[i], mx);
      float al = __expf(m_i[i] - mnew);
      float rs = 0.f;
      #pragma unroll
      for (int j = 0; j < 4; ++j) { float p = __expf(s[i][j] - mnew); s[i][j] = p; rs += p; }
      #pragma unroll
      for (int off = 8; off; off >>= 1) rs += __shfl_xor(rs, off, 64);
      l_i[i] = l_i[i] * al + rs;
      m_i[i] = mnew;
      #pragma unroll
      for (int j = 0; j < 4; ++j) o[i][j] *= al;
    }
    __syncthreads();
    #pragma unroll
    for (int i = 0; i < 4; ++i)
      #pragma unroll
      for (int j = 0; j < 4; ++j)
        KPs[tx * 4 + j][ty * 4 + i] = s[i][j];
    __syncthreads();
    #pragma unroll 8
    for (int c = 0; c < 64; ++c) {
      float4 p = *(const float4*)&KPs[c][ty * 4];
      float4 vv = *(const float4*)&Vs[c][tx * 4];
      float pv[4] = {p.x, p.y, p.z, p.w};
      float vvv[4] = {vv.x, vv.y, vv.z, vv.w};
      #pragma unroll
      for (int i = 0; i < 4; ++i)
        #pragma unroll
        for (int j = 0; j < 4; ++j)
          o[i][j] += pv[i] * vvv[j];
    }
  }
  #pragma unroll
  for (int i = 0; i < 4; ++i) {
    float inv = 1.0f / l_i[i];
    float4 ov;
    ov.x = o[i][0] * inv; ov.y = o[i][1] * inv; ov.z = o[i][2] * inv; ov.w = o[i][3] * inv;
    float* dst = ao + ((size_t)(b * TT + q0 + ty * 4 + i)) * (NHEADS * HDIM) + h * HDIM + tx * 4;
    *(float4*)dst = ov;
  }
}

// ---------------- Router top-k: one wave per token ----------------
__global__ __launch_bounds__(64) void topk_kernel(
    const float* __restrict__ logits, int* __restrict__ tki,
    float* __restrict__ tkw, int* __restrict__ counts)
{
  int n = blockIdx.x;
  int e = threadIdx.x;
  float cur = logits[(size_t)n * NE + e];
  float mymv = 0.f; int mymi = 0;
  float mx0 = 0.f, ssum = 0.f;
  for (int it = 0; it < TOPK; ++it) {
    float mv = cur; int mi = e;
    #pragma unroll
    for (int off = 32; off; off >>= 1) {
      float ov = __shfl_xor(mv, off, 64);
      int oi = __shfl_xor(mi, off, 64);
      if (ov > mv || (ov == mv && oi < mi)) { mv = ov; mi = oi; }
    }
    if (it == 0) mx0 = mv;
    ssum += __expf(mv - mx0);
    if (e == it) { mymv = mv; mymi = mi; }
    if (e == mi) cur = -3.0e38f;
  }
  if (e < TOPK) {
    tki[n * TOPK + e] = mymi;
    tkw[n * TOPK + e] = __expf(mymv - mx0) / ssum;
    atomicAdd(&counts[mymi], 1);
  }
}

__global__ void scan_kernel(const int* __restrict__ counts,
    int* __restrict__ offs, int* __restrict__ curs)
{
  if (threadIdx.x == 0 && blockIdx.x == 0) {
    int acc = 0;
    for (int e = 0; e < NE; ++e) { offs[e] = acc; curs[e] = acc; acc += counts[e]; }
    offs[NE] = acc;
  }
}

__global__ void fill_kernel(const int* __restrict__ tki,
    const float* __restrict__ tkw, int* __restrict__ curs,
    int* __restrict__ slott, float* __restrict__ slotw)
{
  int i = blockIdx.x * blockDim.x + threadIdx.x;
  if (i >= NTOK * TOPK) return;
  int e = tki[i];
  int pos = atomicAdd(&curs[e], 1);
  slott[pos] = i >> 3;
  slotw[pos] = tkw[i];
}

// ---------------- fp32 -> bf16 flat convert ----------------
__global__ __launch_bounds__(256) void cvt_bf16_kernel(
    const float* __restrict__ src, u16* __restrict__ dst)
{
  int i = blockIdx.x * 256 + threadIdx.x;
  float4 v = ((const float4*)src)[i];
  bf16x4 o;
  o.x = (short)f2bf(v.x); o.y = (short)f2bf(v.y);
  o.z = (short)f2bf(v.z); o.w = (short)f2bf(v.w);
  *(bf16x4*)&dst[(size_t)i * 4] = o;
}

// ------- weight transpose+convert: W[e][K][N] fp32 -> Wt[e][N][K] bf16 -----
__global__ __launch_bounds__(256) void transpose_bf16_kernel(
    const float* __restrict__ W, u16* __restrict__ Wt, int K, int N)
{
  int e = blockIdx.z;
  int n0 = blockIdx.x * 64, k0 = blockIdx.y * 64;
  __shared__ float tile[64][65];
  const float* We = W + (size_t)e * K * N;
  u16* WtE = Wt + (size_t)e * K * N;
  int t = threadIdx.x;
  int r = t >> 4, c4 = (t & 15) * 4;
  #pragma unroll
  for (int i = 0; i < 4; ++i) {
    float4 v = *(const float4*)&We[(size_t)(k0 + r + 16 * i) * N + n0 + c4];
    tile[r + 16 * i][c4 + 0] = v.x; tile[r + 16 * i][c4 + 1] = v.y;
    tile[r + 16 * i][c4 + 2] = v.z; tile[r + 16 * i][c4 + 3] = v.w;
  }
  __syncthreads();
  #pragma unroll
  for (int i = 0; i < 4; ++i) {
    int lin = t + i * 256;
    int n = lin >> 4, kk = (lin & 15) * 4;
    bf16x4 o;
    o.x = (short)f2bf(tile[kk + 0][n]);
    o.y = (short)f2bf(tile[kk + 1][n]);
    o.z = (short)f2bf(tile[kk + 2][n]);
    o.w = (short)f2bf(tile[kk + 3][n]);
    *(bf16x4*)&WtE[(size_t)(n0 + n) * K + k0 + kk] = o;
  }
}

// -------- MoE gate+up fused bf16 MFMA: tile 128M x 64N (x2 matrices) -------
// grid (II/64 = 8, NE); M-tiles looped inside the block.
__global__ __launch_bounds__(256) void moe_gateup_mfma(
    const u16* __restrict__ fb, const u16* __restrict__ WgT,
    const u16* __restrict__ WuT, const int* __restrict__ offs,
    const int* __restrict__ slott, u16* __restrict__ gbuf)
{
  int e = blockIdx.y;
  int base = offs[e];
  int Me = offs[e + 1] - base;
  if (Me <= 0) return;
  int n0 = blockIdx.x * 64;
  int t = threadIdx.x;
  int lane = t & 63, w = t >> 6;
  int lr = lane & 15, q = lane >> 4;

  __shared__ u16 As[128][72];
  __shared__ u16 Bg[64][72];
  __shared__ u16 Bu[64][72];
  __shared__ int rowtok[128];

  const u16* WgE = WgT + (size_t)e * II * HH;   // [n][k]
  const u16* WuE = WuT + (size_t)e * II * HH;

  for (int m0 = 0; m0 < Me; m0 += 128) {
    __syncthreads();   // protect LDS + rowtok from previous m-tile readers
    if (t < 128) {
      int rr = m0 + t;
      rowtok[t] = slott[base + (rr < Me ? rr : Me - 1)];
    }
    f32x4 accg[2][4], accu[2][4];
    #pragma unroll
    for (int mt = 0; mt < 2; ++mt)
      #pragma unroll
      for (int nt = 0; nt < 4; ++nt) {
        accg[mt][nt] = (f32x4)0.f;
        accu[mt][nt] = (f32x4)0.f;
      }
    for (int k0 = 0; k0 < HH; k0 += 64) {
      __syncthreads();
      #pragma unroll
      for (int i = 0; i < 4; ++i) {       // A: 128x64 bf16 gathered rows of f
        int lin = t + i * 256;
        int row = lin >> 3, c8 = (lin & 7) * 8;
        *(bf16x8*)&As[row][c8] =
            *(const bf16x8*)&fb[(size_t)rowtok[row] * HH + k0 + c8];
      }
      #pragma unroll
      for (int i = 0; i < 2; ++i) {       // B: 64x64 each, [n][k] contiguous
        int lin = t + i * 256;
        int n = lin >> 3, c8 = (lin & 7) * 8;
        *(bf16x8*)&Bg[n][c8] = *(const bf16x8*)&WgE[(size_t)(n0 + n) * HH + k0 + c8];
        *(bf16x8*)&Bu[n][c8] = *(const bf16x8*)&WuE[(size_t)(n0 + n) * HH + k0 + c8];
      }
      __syncthreads();
      #pragma unroll
      for (int ks = 0; ks < 64; ks += 32) {
        bf16x8 af[2], bgf[4], buf4[4];
        #pragma unroll
        for (int mt = 0; mt < 2; ++mt)
          af[mt] = *(const bf16x8*)&As[w * 32 + mt * 16 + lr][ks + q * 8];
        #pragma unroll
        for (int nt = 0; nt < 4; ++nt) {
          bgf[nt]  = *(const bf16x8*)&Bg[nt * 16 + lr][ks + q * 8];
          buf4[nt] = *(const bf16x8*)&Bu[nt * 16 + lr][ks + q * 8];
        }
        #pragma unroll
        for (int mt = 0; mt < 2; ++mt)
          #pragma unroll
          for (int nt = 0; nt < 4; ++nt) {
            accg[mt][nt] = __builtin_amdgcn_mfma_f32_16x16x32_bf16(
                af[mt], bgf[nt], accg[mt][nt], 0, 0, 0);
            accu[mt][nt] = __builtin_amdgcn_mfma_f32_16x16x32_bf16(
                af[mt], buf4[nt], accu[mt][nt], 0, 0, 0);
          }
      }
    }
    // epilogue: silu(g)*u -> bf16 g buffer. D layout: row=(q*4+i), col=lr.
    #pragma unroll
    for (int mt = 0; mt < 2; ++mt) {
      #pragma unroll
      for (int i = 0; i < 4; ++i) {
        int row = w * 32 + mt * 16 + q * 4 + i;
        if (m0 + row >= Me) continue;
        size_t slot = (size_t)(base + m0 + row);
        #pragma unroll
        for (int nt = 0; nt < 4; ++nt) {
          float gv = accg[mt][nt][i];
          float uv = accu[mt][nt][i];
          float val = (gv / (1.f + __expf(-gv))) * uv;
          gbuf[slot * II + n0 + nt * 16 + lr] = f2bf(val);
        }
      }
    }
  }
}

// -------- MoE down bf16 MFMA: tile 128M x 64N, weighted atomic scatter -----
// grid (HH/64 = 16, NE)
__global__ __launch_bounds__(256) void moe_down_mfma(
    const u16* __restrict__ gbuf, const u16* __restrict__ WdT,
    const int* __restrict__ offs, const int* __restrict__ slott,
    const float* __restrict__ slotw, float* __restrict__ out)
{
  int e = blockIdx.y;
  int base = offs[e];
  int Me = offs[e + 1] - base;
  if (Me <= 0) return;
  int n0 = blockIdx.x * 64;
  int t = threadIdx.x;
  int lane = t & 63, w = t >> 6;
  int lr = lane & 15, q = lane >> 4;

  __shared__ u16 As[128][72];
  __shared__ u16 Bs[64][72];

  const u16* WdE = WdT + (size_t)e * HH * II;   // [n=1024][k=512]

  for (int m0 = 0; m0 < Me; m0 += 128) {
    f32x4 acc[2][4];
    #pragma unroll
    for (int mt = 0; mt < 2; ++mt)
      #pragma unroll
      for (int nt = 0; nt < 4; ++nt) acc[mt][nt] = (f32x4)0.f;
    for (int k0 = 0; k0 < II; k0 += 64) {
      __syncthreads();
      #pragma unroll
      for (int i = 0; i < 4; ++i) {       // A: 128x64 from g (slot-contiguous)
        int lin = t + i * 256;
        int row = lin >> 3, c8 = (lin & 7) * 8;
        int rr = m0 + row; if (rr >= Me) rr = Me - 1;
        *(bf16x8*)&As[row][c8] =
            *(const bf16x8*)&gbuf[(size_t)(base + rr) * II + k0 + c8];
      }
      #pragma unroll
      for (int i = 0; i < 2; ++i) {       // B: 64x64 [n][k]
        int lin = t + i * 256;
        int n = lin >> 3, c8 = (lin & 7) * 8;
        *(bf16x8*)&Bs[n][c8] = *(const bf16x8*)&WdE[(size_t)(n0 + n) * II + k0 + c8];
      }
      __syncthreads();
      #pragma unroll
      for (int ks = 0; ks < 64; ks += 32) {
        bf16x8 af[2], bf[4];
        #pragma unroll
        for (int mt = 0; mt < 2; ++mt)
          af[mt] = *(const bf16x8*)&As[w * 32 + mt * 16 + lr][ks + q * 8];
        #pragma unroll
        for (int nt = 0; nt < 4; ++nt)
          bf[nt] = *(const bf16x8*)&Bs[nt * 16 + lr][ks + q * 8];
        #pragma unroll
        for (int mt = 0; mt < 2; ++mt)
          #pragma unroll
          for (int nt = 0; nt < 4; ++nt)
            acc[mt][nt] = __builtin_amdgcn_mfma_f32_16x16x32_bf16(
                af[mt], bf[nt], acc[mt][nt], 0, 0, 0);
      }
    }
    __syncthreads();   // done reading As/Bs before next m-tile overwrites
    #pragma unroll
    for (int mt = 0; mt < 2; ++mt) {
      #pragma unroll
      for (int i = 0; i < 4; ++i) {
        int row = w * 32 + mt * 16 + q * 4 + i;
        if (m0 + row >= Me) continue;
        int slot = base + m0 + row;
        int tok = slott[slot];
        float wgt = slotw[slot];
        #pragma unroll
        for (int nt = 0; nt < 4; ++nt)
          atomicAdd(&out[(size_t)tok * HH + n0 + nt * 16 + lr],
                    wgt * acc[mt][nt][i]);
      }
    }
  }
}

__global__ void copy_kernel(const float* __restrict__ src, float* __restrict__ dst)
{
  int i = blockIdx.x * blockDim.x + threadIdx.x;
  ((float4*)dst)[i] = ((const float4*)src)[i];
}

extern "C" void kernel_launch(void* const* d_in, const int* in_sizes, int n_in,
                              void* d_out, int out_size, void* d_ws, size_t ws_size,
                              hipStream_t stream)
{
  const float* x    = (const float*)d_in[0];
  const float* cosb = (const float*)d_in[1];
  const float* sinb = (const float*)d_in[2];
  const float* ln1  = (const float*)d_in[3];
  const float* ln2  = (const float*)d_in[4];
  const float* Wq   = (const float*)d_in[5];
  const float* Wk   = (const float*)d_in[6];
  const float* Wv   = (const float*)d_in[7];
  const float* Wo   = (const float*)d_in[8];
  const float* Wr   = (const float*)d_in[9];
  const float* Wg   = (const float*)d_in[10];
  const float* Wu   = (const float*)d_in[11];
  const float* Wd   = (const float*)d_in[12];
  float* out = (float*)d_out;
  float* logits = out + (size_t)NTOK * HH;

  float* ws = (float*)d_ws;
  float* h     = ws;
  float* qb    = h   + (size_t)NTOK * HH;
  float* kb    = qb  + (size_t)NTOK * HH;
  float* vb    = kb  + (size_t)NTOK * NKVH * HDIM;
  float* ao    = vb  + (size_t)NTOK * NKVH * HDIM;
  float* x2    = ao  + (size_t)NTOK * HH;
  float* f     = x2  + (size_t)NTOK * HH;
  u16* f_bf    = (u16*)(f + (size_t)NTOK * HH);
  u16* g_bf    = f_bf + (size_t)NTOK * HH;
  u16* WgT     = g_bf + (size_t)NTOK * TOPK * II;
  u16* WuT     = WgT + (size_t)NE * II * HH;
  u16* WdT     = WuT + (size_t)NE * II * HH;
  float* slotw = (float*)(WdT + (size_t)NE * II * HH);
  float* tkw   = slotw + NTOK * TOPK;
  int* tki     = (int*)(tkw + NTOK * TOPK);
  int* slott   = tki + NTOK * TOPK;
  int* counts  = slott + NTOK * TOPK;
  int* offs    = counts + NE;
  int* curs    = offs + NE + 1;

  // MoE weight transpose+convert: [e][K][N] fp32 -> [e][N][K] bf16
  transpose_bf16_kernel<<<dim3(8, 16, 64), 256, 0, stream>>>(Wg, WgT, HH, II);
  transpose_bf16_kernel<<<dim3(8, 16, 64), 256, 0, stream>>>(Wu, WuT, HH, II);
  transpose_bf16_kernel<<<dim3(16, 8, 64), 256, 0, stream>>>(Wd, WdT, II, HH);

  // attention branch (fp32 — keeps router logits / top-k bit-identical to R1)
  rmsnorm_kernel<<<NTOK, 256, 0, stream>>>(x, ln1, h);
  gemm_kernel<<<dim3(16, 32), 256, 0, stream>>>(h, Wq, qb, nullptr, NTOK, 1024, 1024);
  gemm_kernel<<<dim3(4, 32), 256, 0, stream>>>(h, Wk, kb, nullptr, NTOK, 256, 1024);
  gemm_kernel<<<dim3(4, 32), 256, 0, stream>>>(h, Wv, vb, nullptr, NTOK, 256, 1024);
  rope_kernel<<<4096, 256, 0, stream>>>(qb, cosb, sinb, NHEADS);
  rope_kernel<<<1024, 256, 0, stream>>>(kb, cosb, sinb, NKVH);
  attn_kernel<<<dim3(16, 32), 256, 0, stream>>>(qb, kb, vb, ao);
  gemm_kernel<<<dim3(16, 32), 256, 0, stream>>>(ao, Wo, x2, x, NTOK, 1024, 1024);

  // router (fp32)
  rmsnorm_kernel<<<NTOK, 256, 0, stream>>>(x2, ln2, f);
  gemm_kernel<<<dim3(1, 32), 256, 0, stream>>>(f, Wr, logits, nullptr, NTOK, 64, 1024);
  hipMemsetAsync(counts, 0, NE * sizeof(int), stream);
  topk_kernel<<<NTOK, 64, 0, stream>>>(logits, tki, tkw, counts);
  scan_kernel<<<1, 64, 0, stream>>>(counts, offs, curs);
  fill_kernel<<<64, 256, 0, stream>>>(tki, tkw, curs, slott, slotw);

  // MoE expert compute (bf16 MFMA)
  cvt_bf16_kernel<<<2048, 256, 0, stream>>>(f, f_bf);
  moe_gateup_mfma<<<dim3(8, 64), 256, 0, stream>>>(f_bf, WgT, WuT, offs, slott, g_bf);
  copy_kernel<<<2048, 256, 0, stream>>>(x2, out);
  moe_down_mfma<<<dim3(16, 64), 256, 0, stream>>>(g_bf, WdT, offs, slott, slotw, out);
}